// Round 8
// baseline (176.605 us; speedup 1.0000x reference)
//
#include <hip/hip_runtime.h>
#include <math.h>

// SSIM fused single pass, v13.
// History: v5 = 67.2us/disp (VALUBusy 52%, HBM 12%, VGPR 80, 0 conflicts).
//   v6  (pipelined staging, no fence)  NEUTRAL -> LDS/vmcnt roundtrip not the stall.
//   v7  (TY=23, imbalanced grid)       REGRESS -> straggler CUs, invalid test.
//   v8  (macro self-init UB)           ABORT.
//   v9  (26-phase full unroll ~70KB)   REGRESS 148us.
//   v10 (6 blk/CU, 35KB body)          REGRESS 107us.
//   v11 (rolled 3.5KB body, 3 blk/CU)  ~NEUTRAL 69.9us, busy 56%.
//   v12 (rolled body, 6 blk/CU)        82.2us = 69.9 x 1.18 halo tax, busy 54%:
//        doubling dispatched waves bought ZERO stall reduction.
// Lead anomaly: OccupancyPercent ~25-27% in BOTH v5 (12 waves/CU dispatched)
// and v12 (24 dispatched) => measured residency pinned at ~8 waves/CU (~2
// blocks of 256 threads). VGPR(80) and LDS(9.2KB) don't explain a 2-block
// cap -> suspect per-CU workgroup packing for big-LDS 256-thread blocks.
// v13 = make blocks trivially packable:
//  * 1-WAVE blocks (64 thr): block = one wave, one 128-col strip, TY=34
//    rows -- per-wave work IDENTICAL to v5 (no halo tax, clean A/B).
//  * grid (64,48) = 3072 blocks = exactly 12 blocks/CU, balanced.
//  * LDS/block 9216 -> 2304 B; no barriers at all (wave shuffle reduce +
//    one atomicAdd per block; red[]/syncthreads deleted).
//  * __threadfence_block dropped: in-loop lgkmcnt is DS-only (SMEM drained
//    in prologue), a wave's DS ops complete IN ORDER, so the compiler's
//    own lgkmcnt-before-use of e[] already covers the staged writes.
// Pre-committed: Fork A (cap was packing): occ >=37%, busy >=70%, ~50-55us.
// Fork B (null ~68-70us): occupancy lever conclusively dead; pivot to ops.

#define KW 11
#define RAD 5
#define IMG_W 512
#define IMG_H 512
#define TY 34                // output rows per wave tile
#define NPH (TY + 2 * RAD)   // 44 phases
#define NV4 70               // 140 staged (a,b) pairs = 70 v4f per row buffer
#define C1F 0.0001f          // 0.01^2
#define C2F 0.0009f          // 0.03^2

typedef float v2f __attribute__((ext_vector_type(2)));
typedef float v4f __attribute__((ext_vector_type(4)));

struct GaussW { float g[KW]; };

__global__ __launch_bounds__(64) void ssim_fused_kernel(
    const float* __restrict__ img1,
    const float* __restrict__ img2,
    float* __restrict__ out,
    float inv_n,
    GaussW gw)
{
    __shared__ v4f rows[2][NV4];   // [double-buffer][v4f = 2 (a,b) pairs], 2240 B

    const int lane = threadIdx.x;          // 0..63, one wave per block

    const int x0 = (blockIdx.x & 3) * 128;     // strip 0..3
    const int y0 = (blockIdx.x >> 2) * TY;     // y-tile 0..15

    const size_t pbase = (size_t)blockIdx.y * (size_t)(IMG_W * IMG_H);
    const float* __restrict__ p1 = img1 + pbase;
    const float* __restrict__ p2 = img2 + pbase;

    // Gaussian weights: by-value kernarg -> SGPRs (wave-uniform).
    float g[KW];
    #pragma unroll
    for (int i = 0; i < KW; ++i) g[i] = gw.g[i];

    // Staged entries cover cols x0-6 .. x0+133 (140 entries, even start for
    // aligned float2 loads). Lane t owns entries {2t, 2t+1}; lanes 0..5 also
    // stage halo entries {128+2l, 129+2l}.
    const int cm  = x0 - 6 + 2 * lane;                 // main col (even)
    const int cmc = min(max(cm, 0), IMG_W - 2);        // clamped, even
    const float mm0 = (cm     >= 0 && cm     < IMG_W) ? 1.f : 0.f;
    const float mm1 = (cm + 1 >= 0 && cm + 1 < IMG_W) ? 1.f : 0.f;
    const int ch  = x0 + 122 + 2 * lane;               // halo col (lanes 0..5)
    const int chc = min(max(ch, 0), IMG_W - 2);
    const float mh0 = (ch     < IMG_W) ? 1.f : 0.f;
    const float mh1 = (ch + 1 < IMG_W) ? 1.f : 0.f;

    // Load row (y0-RAD+j) into interleaved+masked (a0,b0,a1,b1) v4f regs.
    auto load_row = [&](int j, v4f& vm, v4f& vh) {
        const int ir = y0 - RAD + j;
        vm = (v4f){0.f, 0.f, 0.f, 0.f};
        vh = (v4f){0.f, 0.f, 0.f, 0.f};
        if ((unsigned)ir < (unsigned)IMG_H) {   // wave-uniform branch
            const float* r1 = p1 + ir * IMG_W;
            const float* r2 = p2 + ir * IMG_W;
            const v2f a = *reinterpret_cast<const v2f*>(r1 + cmc);
            const v2f b = *reinterpret_cast<const v2f*>(r2 + cmc);
            vm = (v4f){a.x * mm0, b.x * mm0, a.y * mm1, b.y * mm1};
            if (lane < 6) {
                const v2f ah = *reinterpret_cast<const v2f*>(r1 + chc);
                const v2f bh = *reinterpret_cast<const v2f*>(r2 + chc);
                vh = (v4f){ah.x * mh0, bh.x * mh0, ah.y * mh1, bh.y * mh1};
            }
        }
    };

    // Value-rotating V accumulators: slot t completes in t more phases.
    // (mu1,mu2) and (S,P) per px for the thread's 2 columns A=2lane, B=2lane+1.
    // 10 live slots (the 11th tap is applied at emit).
    v2f aMuA[KW - 1], aSPA[KW - 1], aMuB[KW - 1], aSPB[KW - 1];
    #pragma unroll
    for (int t = 0; t < KW - 1; ++t) {
        aMuA[t] = (v2f){0.f, 0.f}; aSPA[t] = (v2f){0.f, 0.f};
        aMuB[t] = (v2f){0.f, 0.f}; aSPB[t] = (v2f){0.f, 0.f};
    }

    v4f curm, curh;
    load_row(0, curm, curh);

    float acc = 0.f;

    // ROLLED phase loop (~3.5KB body, I$ resident). No fence/barrier: the
    // wave's DS ops complete in order; compiler's lgkmcnt before e[] use
    // already guarantees W_j < R_j data visibility.
    #pragma clang loop unroll(disable)
    for (int j = 0; j < NPH; ++j) {
        v4f* __restrict__ wrow = rows[j & 1];

        // ---- stage row j (regs -> wave-private LDS) ----
        wrow[lane] = curm;                          // ds_write_b128
        if (lane < 6) wrow[64 + lane] = curh;

        // ---- prefetch row j+1 (latency covered by this iter's math) ----
        if (j < NPH - 1) load_row(j + 1, curm, curh);

        // ---- read the 14-pair window: v4f slots lane..lane+6 ----
        v4f e[7];
        #pragma unroll
        for (int r = 0; r < 7; ++r) e[r] = wrow[lane + r];   // ds_read_b128

        // pairs: idx 0..13; pair(i) = i even ? e[i/2].xy : e[i/2].zw
        // window for col A uses pairs 1..11, col B uses pairs 2..12.
        v2f ab[14], sp[14];
        #pragma unroll
        for (int i = 0; i < 14; ++i) {
            const v4f q = e[i >> 1];
            ab[i] = (i & 1) ? (v2f){q.z, q.w} : (v2f){q.x, q.y};
        }
        #pragma unroll
        for (int i = 1; i <= 12; ++i) {
            const v2f t = ab[i];
            sp[i] = (v2f){fmaf(t.x, t.x, t.y * t.y), t.x * t.y};
        }

        // ---- horizontal 11-tap conv, 2 px, packed ----
        v2f hMuA = (v2f){0.f, 0.f}, hSPA = (v2f){0.f, 0.f};
        v2f hMuB = (v2f){0.f, 0.f}, hSPB = (v2f){0.f, 0.f};
        #pragma unroll
        for (int k = 0; k < KW; ++k) {
            const v2f gk = (v2f){g[k], g[k]};
            hMuA = __builtin_elementwise_fma(gk, ab[1 + k], hMuA);
            hSPA = __builtin_elementwise_fma(gk, sp[1 + k], hSPA);
            hMuB = __builtin_elementwise_fma(gk, ab[2 + k], hMuB);
            hSPB = __builtin_elementwise_fma(gk, sp[2 + k], hSPB);
        }

        // ---- emit output row oy = y0 + j - 10: last tap g[10] applied
        //      directly against acc[0] (read BEFORE the fused shift) ----
        const int oy = y0 + j - 2 * RAD;
        if (j >= 2 * RAD && oy < IMG_H) {   // wave-uniform
            const v2f g10 = (v2f){g[KW - 1], g[KW - 1]};
            #pragma unroll
            for (int px = 0; px < 2; ++px) {
                const v2f mu = __builtin_elementwise_fma(
                    g10, px ? hMuB : hMuA, px ? aMuB[0] : aMuA[0]);
                const v2f SP = __builtin_elementwise_fma(
                    g10, px ? hSPB : hSPA, px ? aSPB[0] : aSPA[0]);
                const v2f musq = mu * mu;
                const float mu12  = mu.x * mu.y;
                const float musum = musq.x + musq.y;
                const float ssum  = SP.x - musum;          // sigma1^2+sigma2^2
                const float s12   = SP.y - mu12;           // sigma12
                const float num = fmaf(2.f, mu12, C1F) * fmaf(2.f, s12, C2F);
                const float den = (musum + C1F) * (ssum + C2F);
                acc = fmaf(num, __builtin_amdgcn_rcpf(den), acc);
            }
        }

        // ---- fused shift+scatter (ascending t reads old acc[t+1]):
        //      slot t gets tap g[9-t]; same tap order per output as v5 ----
        #pragma unroll
        for (int t = 0; t < KW - 2; ++t) {   // t = 0..8
            const v2f w = (v2f){g[KW - 2 - t], g[KW - 2 - t]};   // g[9-t]
            aMuA[t] = __builtin_elementwise_fma(w, hMuA, aMuA[t + 1]);
            aSPA[t] = __builtin_elementwise_fma(w, hSPA, aSPA[t + 1]);
            aMuB[t] = __builtin_elementwise_fma(w, hMuB, aMuB[t + 1]);
            aSPB[t] = __builtin_elementwise_fma(w, hSPB, aSPB[t + 1]);
        }
        {   // birth: newest slot, first tap g[0] (assign)
            const v2f g0 = (v2f){g[0], g[0]};
            aMuA[KW - 2] = g0 * hMuA;  aSPA[KW - 2] = g0 * hSPA;
            aMuB[KW - 2] = g0 * hMuB;  aSPB[KW - 2] = g0 * hSPB;
        }
    }

    // ---- wave reduction, one atomic per block (no barrier needed) ----
    #pragma unroll
    for (int off = 32; off > 0; off >>= 1)
        acc += __shfl_xor(acc, off, 64);
    if (lane == 0) atomicAdd(out, acc * inv_n);
}

extern "C" void kernel_launch(void* const* d_in, const int* in_sizes, int n_in,
                              void* d_out, int out_size, void* d_ws, size_t ws_size,
                              hipStream_t stream) {
    (void)in_sizes; (void)n_in; (void)d_ws; (void)ws_size;
    const float* img1 = (const float*)d_in[0];
    const float* img2 = (const float*)d_in[1];
    float* out = (float*)d_out;

    // d_out is re-poisoned to 0xAA before every launch; zero it (capture-safe).
    hipMemsetAsync(out, 0, (size_t)out_size * sizeof(float), stream);

    // Gaussian weights on host, double precision (same math as the original
    // device prologue); float-rounded -> identical weights (absmax 0.0 in
    // v7/v10/v11/v12 benches).
    GaussW gw;
    {
        double t[KW];
        double s = 0.0;
        for (int i = 0; i < KW; ++i) {
            const double c = (double)(i - RAD);
            t[i] = exp(-(c * c) / 4.5);   // 2*sigma^2 = 4.5
            s += t[i];
        }
        for (int i = 0; i < KW; ++i) gw.g[i] = (float)(t[i] / s);
    }

    const float inv_n = 1.0f / (16.0f * 3.0f * 512.0f * 512.0f);
    // 1-wave blocks: grid.x = 4 strips x 16 y-tiles = 64; grid.y = 48 planes.
    // 3072 blocks = exactly 12 blocks/CU (balanced), 12 waves/CU dispatched.
    dim3 grid(64, 48, 1);
    ssim_fused_kernel<<<grid, dim3(64, 1, 1), 0, stream>>>(img1, img2, out, inv_n, gw);
}